// Round 1
// baseline (574.993 us; speedup 1.0000x reference)
//
#include <hip/hip_runtime.h>
#include <hip/hip_bf16.h>

// Problem: B=32, S=2048, D=1024, SIZE=1024
//   term1[b,s,k] = sum_d WO[k,d]*inputs[b,s,d]   (GEMM M=65536,N=1024,K=1024)
//   term2[b,k]   = sum_d WG[k,d]*g[b,d]
//   out[b,s]     = sum_k v[k]*tanh(term1+term2)
#define BB   32
#define SS   2048
#define DD   1024
#define SZ   1024
#define MM   (BB*SS)   // 65536

typedef short bf16x8 __attribute__((ext_vector_type(8)));
typedef float f32x4  __attribute__((ext_vector_type(4)));

__device__ __forceinline__ unsigned short f2bf(float x) {
    // round-to-nearest-even fp32 -> bf16 (inputs are finite normals)
    unsigned u = __float_as_uint(x);
    u += 0x7fffu + ((u >> 16) & 1u);
    return (unsigned short)(u >> 16);
}
__device__ __forceinline__ unsigned pack2_bf16(float a, float b) {
    return (unsigned)f2bf(a) | ((unsigned)f2bf(b) << 16);
}

__device__ __forceinline__ float ftanh(float x) {
    // tanh(x) = 1 - 2/(exp(2x)+1); saturates correctly for large |x|
    float e = __expf(2.0f * x);
    return 1.0f - 2.0f / (e + 1.0f);
}

// ---------------- prep ------------------------------------------------------
// WO fp32 -> bf16 in TILED layout: WOb[(d>>5)][ (d>>3)&3 ][q][ d&7 ]
//   (so the main kernel's linear global_load_lds write produces a
//    conflict-free [kg][n][8] LDS layout for the B fragments)
// term2 = WG @ g[b] (fp32), unchanged.
__global__ void prep_kernel(const float* __restrict__ WO,
                            const float* __restrict__ WG,
                            const float* __restrict__ g,
                            unsigned short* __restrict__ WOb,
                            float* __restrict__ term2) {
    __shared__ float gs[DD];
    int bid = blockIdx.x, tid = threadIdx.x;
    if (bid < 1024) {
        int q = bid;            // WO row (the GEMM n index)
        int d = tid * 4;        // 4 consecutive d per thread
        float4 w = *(const float4*)(WO + (size_t)q * DD + d);
        unsigned p0 = pack2_bf16(w.x, w.y), p1 = pack2_bf16(w.z, w.w);
        int dst = ((d >> 5) * 4096 + ((d >> 3) & 3) * 1024 + q) * 8 + (d & 7);
        *(uint2*)&WOb[dst] = make_uint2(p0, p1);
    } else {
        int id = bid - 1024;           // 0..127
        int b  = id >> 2;              // batch
        int k  = ((id & 3) << 8) + tid;
        #pragma unroll
        for (int r = 0; r < 4; r++) gs[r * 256 + tid] = g[b * DD + r * 256 + tid];
        __syncthreads();
        const float* wr = WG + (size_t)k * DD;
        float s = 0.f;
        #pragma unroll 4
        for (int d = 0; d < DD; d += 4) {
            float4 wv = *(const float4*)(wr + d);
            s += wv.x * gs[d] + wv.y * gs[d + 1] + wv.z * gs[d + 2] + wv.w * gs[d + 3];
        }
        term2[b * SZ + k] = s;
    }
}

// ---------------- main: fused GEMM + tanh + v-reduction ---------------------
// block tile 128(M) x 256(N), BK=32; 4 waves, each 64x128 (4x8 of 16x16x32).
// Double-buffered LDS, ONE barrier per K-step:
//   issue A(t+1)->regs + B(t+1)->LDS(buf^1)  |  ds_read+MFMA(buf)  |
//   cvt+write A(t+1)->LDS(buf^1)  |  barrier
// LDS layouts are [kg][row][8] so every ds_read_b128 group of 16 lanes reads
// 256 consecutive bytes -> zero bank conflicts (A and B).
__global__ __launch_bounds__(256, 2) void fused_main(
    const float* __restrict__ Ain,            // [MM, DD] fp32
    const unsigned short* __restrict__ WOb,   // tiled bf16 (see prep)
    const float* __restrict__ term2,          // [BB, SZ] fp32
    const float* __restrict__ v,              // [SZ] fp32
    float* __restrict__ out) {                // [MM] fp32 (pre-zeroed)
    __shared__ unsigned short Asm[2 * 4096];  // [buf][kg 0..3][row 0..127][8]
    __shared__ unsigned short Bsm[2 * 8192];  // [buf][kg 0..3][n 0..255][8]
    __shared__ float part[2][128];

    const int tid  = threadIdx.x;
    const int wave = tid >> 6;
    const int lane = tid & 63;
    const int wm  = wave & 1, wn = wave >> 1;
    const int l15 = lane & 15;
    const int kgl = lane >> 4;                // k-group 0..3 (8 bf16 each)

    // XCD-aware swizzle: physical blocks round-robin XCDs (bid%8); remap so
    // each XCD owns a contiguous logical range -> the 4 n-tile blocks of one
    // m-tile co-run on ONE XCD and share the A m-tile out of that XCD's L2.
    // 2048 blocks, 2048%8==0 -> bijective.
    const int bid     = blockIdx.x;
    const int logical = (bid & 7) * 256 + (bid >> 3);
    const int ntile = logical & 3;
    const int mtile = logical >> 2;
    const int m0 = mtile * 128;
    const int n0 = ntile * 256;
    const int bidx = m0 >> 11;                // batch index (128 | 2048)

    // staging invariants
    const int rowb = tid >> 3;                // A: row within 32-row group
    const int sub  = tid & 7;                 // A: d-quarter 0..7
    const int kgA  = sub >> 1, halfA = sub & 1;

    f32x4 acc[4][8];
    #pragma unroll
    for (int i = 0; i < 4; i++)
        #pragma unroll
        for (int j = 0; j < 8; j++) acc[i][j] = (f32x4){0.f, 0.f, 0.f, 0.f};

    float4 areg[4];

    // --- staging helpers ---
    auto LOAD_A = [&](int k0) {               // fp32 tile (t) -> regs
        #pragma unroll
        for (int r = 0; r < 4; r++) {
            int row = r * 32 + rowb;
            areg[r] = *(const float4*)(Ain + (size_t)(m0 + row) * DD + k0 + sub * 4);
        }
    };
    auto WRITE_A = [&](int buf) {             // regs -> bf16 LDS [kg][row][8]
        #pragma unroll
        for (int r = 0; r < 4; r++) {
            int row = r * 32 + rowb;
            unsigned p0 = pack2_bf16(areg[r].x, areg[r].y);
            unsigned p1 = pack2_bf16(areg[r].z, areg[r].w);
            *(uint2*)&Asm[buf * 4096 + (kgA * 128 + row) * 8 + halfA * 4] =
                make_uint2(p0, p1);
        }
    };
    auto STAGE_B = [&](int buf, int k0) {     // tiled bf16 -> LDS via DMA
        const int dstep = k0 >> 5;
        #pragma unroll
        for (int r = 0; r < 4; r++) {         // round r fills kg=r, n=tid
            const unsigned short* src = WOb + dstep * 32768 + r * 8192 + (n0 + tid) * 8;
            __builtin_amdgcn_global_load_lds(
                (const __attribute__((address_space(1))) void*)src,
                (__attribute__((address_space(3))) void*)(&Bsm[buf * 8192 + (r * 256 + tid) * 8]),
                16, 0, 0);
        }
    };
    auto COMPUTE = [&](int buf) {
        bf16x8 afr[4], bfr[8];
        const int aoff = (kgl * 128 + wm * 64 + l15) * 8;
        const int boff = (kgl * 256 + wn * 128 + l15) * 8;
        #pragma unroll
        for (int mi = 0; mi < 4; mi++)
            afr[mi] = *(const bf16x8*)&Asm[buf * 4096 + aoff + mi * 128];
        #pragma unroll
        for (int ni = 0; ni < 8; ni++)
            bfr[ni] = *(const bf16x8*)&Bsm[buf * 8192 + boff + ni * 128];
        __builtin_amdgcn_s_setprio(1);
        #pragma unroll
        for (int ni = 0; ni < 8; ni++)
            #pragma unroll
            for (int mi = 0; mi < 4; mi++)
                acc[mi][ni] = __builtin_amdgcn_mfma_f32_16x16x32_bf16(
                    afr[mi], bfr[ni], acc[mi][ni], 0, 0, 0);
        __builtin_amdgcn_s_setprio(0);
    };

    // --- prologue: fill buffer 0 ---
    LOAD_A(0);
    STAGE_B(0, 0);
    WRITE_A(0);
    __syncthreads();

    // --- main loop: one barrier per K-step, prefetch depth 1 ---
    for (int t = 0; t < 31; ++t) {
        const int cur = t & 1;
        LOAD_A((t + 1) << 5);           // oldest vmem: areg (so WRITE_A waits
        STAGE_B(cur ^ 1, (t + 1) << 5); //  with counted vmcnt, not a drain)
        COMPUTE(cur);
        WRITE_A(cur ^ 1);
        __syncthreads();
    }
    COMPUTE(1);                          // t=31

    // --- epilogue: tanh(term1+term2)*v, reduce over this block's 256 cols ---
    float rsum[4][4];
    #pragma unroll
    for (int mi = 0; mi < 4; mi++)
        #pragma unroll
        for (int r = 0; r < 4; r++) rsum[mi][r] = 0.f;

    #pragma unroll
    for (int ni = 0; ni < 8; ni++) {
        int gn = n0 + wn * 128 + ni * 16 + l15;   // C/D: col = lane&15
        float t2 = term2[bidx * SZ + gn];
        float vv = v[gn];
        #pragma unroll
        for (int mi = 0; mi < 4; mi++)
            #pragma unroll
            for (int r = 0; r < 4; r++)
                rsum[mi][r] += ftanh(acc[mi][ni][r] + t2) * vv;
    }
    // reduce across the 16 col-lanes (butterfly within 16-lane groups)
    #pragma unroll
    for (int mi = 0; mi < 4; mi++)
        #pragma unroll
        for (int r = 0; r < 4; r++) {
            float s = rsum[mi][r];
            s += __shfl_xor(s, 1, 16);
            s += __shfl_xor(s, 2, 16);
            s += __shfl_xor(s, 4, 16);
            s += __shfl_xor(s, 8, 16);
            rsum[mi][r] = s;
        }
    // lane l15 == mi*4+r publishes row (wm*64 + mi*16 + kgl*4 + r)
    float val = 0.f;
    #pragma unroll
    for (int mi = 0; mi < 4; mi++)
        #pragma unroll
        for (int r = 0; r < 4; r++)
            if (l15 == mi * 4 + r) val = rsum[mi][r];
    {
        int mi = l15 >> 2, r = l15 & 3;
        part[wn][wm * 64 + mi * 16 + kgl * 4 + r] = val;
    }
    __syncthreads();
    if (tid < 128) atomicAdd(&out[m0 + tid], part[0][tid] + part[1][tid]);
}

extern "C" void kernel_launch(void* const* d_in, const int* in_sizes, int n_in,
                              void* d_out, int out_size, void* d_ws, size_t ws_size,
                              hipStream_t stream) {
    const float* inputs = (const float*)d_in[0];   // [32,2048,1024]
    const float* g      = (const float*)d_in[1];   // [32,1024]
    const float* WO     = (const float*)d_in[2];   // [1024,1024]
    const float* WG     = (const float*)d_in[3];   // [1024,1024]
    const float* v      = (const float*)d_in[4];   // [1,1024]
    float* out = (float*)d_out;

    unsigned short* WOb = (unsigned short*)d_ws;                       // 2 MB bf16 WO (tiled)
    float* term2 = (float*)((char*)d_ws + (size_t)SZ * DD * 2);        // 128 KB fp32

    (void)hipMemsetAsync(d_out, 0, sizeof(float) * MM, stream);
    prep_kernel<<<1024 + 128, 256, 0, stream>>>(WO, WG, g, WOb, term2);
    fused_main<<<(MM / 128) * (SZ / 256), 256, 0, stream>>>(inputs, WOb, term2, v, out);
}

// Round 2
// 534.050 us; speedup vs baseline: 1.0767x; 1.0767x over previous
//
#include <hip/hip_runtime.h>
#include <hip/hip_bf16.h>

// Problem: B=32, S=2048, D=1024, SIZE=1024
//   term1[b,s,k] = sum_d WO[k,d]*inputs[b,s,d]   (GEMM M=65536,N=1024,K=1024)
//   term2[b,k]   = sum_d WG[k,d]*g[b,d]
//   out[b,s]     = sum_k v[k]*tanh(term1+term2)
#define BB   32
#define SS   2048
#define DD   1024
#define SZ   1024
#define MM   (BB*SS)   // 65536

typedef short bf16x8 __attribute__((ext_vector_type(8)));
typedef float f32x4  __attribute__((ext_vector_type(4)));

__device__ __forceinline__ unsigned short f2bf(float x) {
    // round-to-nearest-even fp32 -> bf16 (inputs are finite normals)
    unsigned u = __float_as_uint(x);
    u += 0x7fffu + ((u >> 16) & 1u);
    return (unsigned short)(u >> 16);
}
__device__ __forceinline__ unsigned pack2_bf16(float a, float b) {
    return (unsigned)f2bf(a) | ((unsigned)f2bf(b) << 16);
}

__device__ __forceinline__ float ftanh(float x) {
    // tanh(x) = 1 - 2/(exp(2x)+1); saturates correctly for large |x|
    float e = __expf(2.0f * x);
    return 1.0f - 2.0f / (e + 1.0f);
}

// ---------------- prep ------------------------------------------------------
// WO fp32 -> bf16 in TILED layout WOb[kt=d>>5][kg=(d>>3)&3][q][d&7]
//   (main kernel's linear global_load_lds then yields conflict-free
//    [kg][n][8] LDS tiles for the B fragments)
// term2 = WG @ g[b]: one wave per 16 k's, 64-lane coalesced dot + shuffle
// reduce (the old one-thread-per-k version was uncoalesced and low-parallel).
__global__ void prep_kernel(const float* __restrict__ WO,
                            const float* __restrict__ WG,
                            const float* __restrict__ g,
                            unsigned short* __restrict__ WOb,
                            float* __restrict__ term2) {
    int bid = blockIdx.x, tid = threadIdx.x;
    if (bid < 1024) {
        int q = bid;            // WO row (the GEMM n index)
        int d = tid * 4;        // 4 consecutive d per thread
        float4 w = *(const float4*)(WO + (size_t)q * DD + d);
        unsigned p0 = pack2_bf16(w.x, w.y), p1 = pack2_bf16(w.z, w.w);
        int dst = ((d >> 5) * 4096 + ((d >> 3) & 3) * 1024 + q) * 8 + (d & 7);
        *(uint2*)&WOb[dst] = make_uint2(p0, p1);
    } else {
        int id    = bid - 1024;            // 0..511
        int b     = id >> 4;               // batch 0..31
        int wave  = tid >> 6, lane = tid & 63;
        int kbase = (id & 15) * 64 + wave * 16;
        const float* gr = g + (size_t)b * DD + lane * 16;
        float4 g0 = *(const float4*)(gr + 0);
        float4 g1 = *(const float4*)(gr + 4);
        float4 g2 = *(const float4*)(gr + 8);
        float4 g3 = *(const float4*)(gr + 12);
        #pragma unroll
        for (int i = 0; i < 16; i++) {
            int k = kbase + i;
            const float* wr = WG + (size_t)k * DD + lane * 16;
            float4 a0 = *(const float4*)(wr + 0);
            float4 a1 = *(const float4*)(wr + 4);
            float4 a2 = *(const float4*)(wr + 8);
            float4 a3 = *(const float4*)(wr + 12);
            float s = a0.x*g0.x + a0.y*g0.y + a0.z*g0.z + a0.w*g0.w
                    + a1.x*g1.x + a1.y*g1.y + a1.z*g1.z + a1.w*g1.w
                    + a2.x*g2.x + a2.y*g2.y + a2.z*g2.z + a2.w*g2.w
                    + a3.x*g3.x + a3.y*g3.y + a3.z*g3.z + a3.w*g3.w;
            #pragma unroll
            for (int m = 1; m < 64; m <<= 1) s += __shfl_xor(s, m);
            if (lane == 0) term2[b * SZ + k] = s;
        }
    }
}

// ---------------- main: fused GEMM + tanh + v-reduction ---------------------
// block tile 128(M) x 256(N), BK=32; 4 waves, each 64x128 (4x8 of 16x16x32).
// Counted-vmcnt pipeline (T4): raw s_barrier + s_waitcnt vmcnt(4) so the 4
// A-prefetch loads for K(t+2) stay in flight ACROSS the barrier; only the
// B-DMA for K(t+1) is required complete. __syncthreads (vmcnt(0) drain) was
// the 2-phase plateau (m233). vmem issue order pinned with sched_barrier(0):
//   [WRITE_A(t+1)][STAGE_B(t+1) x4][LOAD_A(t+2) x4][COMPUTE(t)]
//   [vmcnt(4) -> B done, A live][lgkmcnt(0)][s_barrier]
// LDS layouts [kg][row][8]: every 16-lane ds_read_b128 group reads 256
// contiguous bytes -> conflict-free; A ds_writes land evenly on all banks.
__global__ __launch_bounds__(256, 2) void fused_main(
    const float* __restrict__ Ain,            // [MM, DD] fp32
    const unsigned short* __restrict__ WOb,   // tiled bf16 (see prep)
    const float* __restrict__ term2,          // [BB, SZ] fp32
    const float* __restrict__ v,              // [SZ] fp32
    float* __restrict__ out) {                // [MM] fp32 (pre-zeroed)
    __shared__ unsigned short Abuf[2][4096];  // [buf][kg 0..3][row 0..127][8]
    __shared__ unsigned short Bbuf[2][8192];  // [buf][kg 0..3][n 0..255][8]
    __shared__ float part[2][128];

    const int tid  = threadIdx.x;
    const int wave = tid >> 6;
    const int lane = tid & 63;
    const int wm  = wave & 1, wn = wave >> 1;
    const int l15 = lane & 15;
    const int k8  = lane >> 4;                // k-group 0..3 (8 bf16 each)

    // XCD-aware bijective swizzle (2048 % 8 == 0): each XCD owns contiguous
    // logical blocks -> the 4 n-tiles of an m-tile share A via that XCD's L2.
    const int bid     = blockIdx.x;
    const int logical = (bid & 7) * 256 + (bid >> 3);
    const int ntile = logical & 3;
    const int mtile = logical >> 2;
    const int m0 = mtile * 128;
    const int n0 = ntile * 256;
    const int bidx = m0 >> 11;                // batch index (128 | 2048)

    f32x4 acc[4][8];
    #pragma unroll
    for (int i = 0; i < 4; i++)
        #pragma unroll
        for (int j = 0; j < 8; j++) acc[i][j] = (f32x4){0.f, 0.f, 0.f, 0.f};

    float4 areg[4];

    // --- staging helpers ---
    auto LOAD_A = [&](int k0) {               // fp32 tile -> regs (4x dwordx4,
        #pragma unroll                        //  8 rows x 128B fully coalesced)
        for (int r = 0; r < 4; r++) {
            int row = r * 32 + (tid >> 3);
            areg[r] = *(const float4*)(Ain + (size_t)(m0 + row) * DD + k0 + (tid & 7) * 4);
        }
    };
    auto WRITE_A = [&](int buf) {             // regs -> bf16 LDS [kg][row][8]
        const int q = tid & 7, kg = q >> 1, half = q & 1;
        #pragma unroll
        for (int r = 0; r < 4; r++) {
            int row = r * 32 + (tid >> 3);
            unsigned p0 = pack2_bf16(areg[r].x, areg[r].y);
            unsigned p1 = pack2_bf16(areg[r].z, areg[r].w);
            *(uint2*)&Abuf[buf][(kg * 128 + row) * 8 + half * 4] = make_uint2(p0, p1);
        }
    };
    auto STAGE_B = [&](int buf, int kt) {     // tiled bf16 -> LDS via DMA
        #pragma unroll
        for (int r = 0; r < 4; r++) {         // round r fills kg=r, n=tid
            const unsigned short* src = WOb + ((size_t)(kt * 4 + r) * 1024 + n0 + tid) * 8;
            __builtin_amdgcn_global_load_lds(
                (const __attribute__((address_space(1))) void*)src,
                (__attribute__((address_space(3))) void*)(&Bbuf[buf][(r * 256 + tid) * 8]),
                16, 0, 0);
        }
    };
    auto COMPUTE = [&](int buf) {
        bf16x8 afr[4], bfr[8];
        const int aoff = (k8 * 128 + wm * 64 + l15) * 8;
        const int boff = (k8 * 256 + wn * 128 + l15) * 8;
        #pragma unroll
        for (int mi = 0; mi < 4; mi++)
            afr[mi] = *(const bf16x8*)&Abuf[buf][aoff + mi * 128];
        #pragma unroll
        for (int ni = 0; ni < 8; ni++)
            bfr[ni] = *(const bf16x8*)&Bbuf[buf][boff + ni * 128];
        __builtin_amdgcn_s_setprio(1);
        #pragma unroll
        for (int ni = 0; ni < 8; ni++)
            #pragma unroll
            for (int mi = 0; mi < 4; mi++)
                acc[mi][ni] = __builtin_amdgcn_mfma_f32_16x16x32_bf16(
                    afr[mi], bfr[ni], acc[mi][ni], 0, 0, 0);
        __builtin_amdgcn_s_setprio(0);
    };

    // --- prologue: fill buffer 0 with K0, preload A(K1) regs ---
    LOAD_A(0);
    WRITE_A(0);                                // compiler waits its own loads
    __builtin_amdgcn_sched_barrier(0);
    STAGE_B(0, 0);
    __builtin_amdgcn_sched_barrier(0);
    LOAD_A(32);                                // A(K1) prefetch
    __builtin_amdgcn_sched_barrier(0);
    asm volatile("s_waitcnt vmcnt(4)" ::: "memory");   // B(K0) done; A(K1) live
    asm volatile("s_waitcnt lgkmcnt(0)" ::: "memory"); // A(K0) ds_writes done
    __builtin_amdgcn_sched_barrier(0);
    __builtin_amdgcn_s_barrier();

    // --- main loop: counted vmcnt, one raw barrier per K-step ---
    for (int t = 0; t < 31; ++t) {
        const int buf = t & 1;
        WRITE_A(buf ^ 1);                      // A(t+1): counted wait on areg
        __builtin_amdgcn_sched_barrier(0);
        STAGE_B(buf ^ 1, t + 1);               // B(t+1) DMA (buf^1 free since
        __builtin_amdgcn_sched_barrier(0);     //  previous barrier)
        LOAD_A(((t + 2 <= 31) ? t + 2 : 31) << 5);  // A(t+2); clamped dummy at
        __builtin_amdgcn_sched_barrier(0);          //  t=30 keeps counts uniform
        COMPUTE(buf);
        __builtin_amdgcn_sched_barrier(0);
        asm volatile("s_waitcnt vmcnt(4)" ::: "memory");   // B(t+1) landed,
        asm volatile("s_waitcnt lgkmcnt(0)" ::: "memory"); // A writes+reads done
        __builtin_amdgcn_sched_barrier(0);
        __builtin_amdgcn_s_barrier();
    }
    COMPUTE(1);                                // t=31

    // --- epilogue: tanh(term1+term2)*v, reduce over this block's 256 cols ---
    float rsum[4][4];
    #pragma unroll
    for (int mi = 0; mi < 4; mi++)
        #pragma unroll
        for (int r = 0; r < 4; r++) rsum[mi][r] = 0.f;

    #pragma unroll
    for (int ni = 0; ni < 8; ni++) {
        int gn = n0 + wn * 128 + ni * 16 + l15;   // C/D: col = lane&15
        float t2 = term2[bidx * SZ + gn];
        float vv = v[gn];
        #pragma unroll
        for (int mi = 0; mi < 4; mi++)
            #pragma unroll
            for (int r = 0; r < 4; r++)
                rsum[mi][r] += ftanh(acc[mi][ni][r] + t2) * vv;
    }
    // reduce across the 16 col-lanes (butterfly within 16-lane groups)
    #pragma unroll
    for (int mi = 0; mi < 4; mi++)
        #pragma unroll
        for (int r = 0; r < 4; r++) {
            float s = rsum[mi][r];
            s += __shfl_xor(s, 1, 16);
            s += __shfl_xor(s, 2, 16);
            s += __shfl_xor(s, 4, 16);
            s += __shfl_xor(s, 8, 16);
            rsum[mi][r] = s;
        }
    // lane l15 == mi*4+r publishes row (wm*64 + mi*16 + k8*4 + r)
    float val = 0.f;
    #pragma unroll
    for (int mi = 0; mi < 4; mi++)
        #pragma unroll
        for (int r = 0; r < 4; r++)
            if (l15 == mi * 4 + r) val = rsum[mi][r];
    {
        int mi = l15 >> 2, r = l15 & 3;
        part[wn][wm * 64 + mi * 16 + k8 * 4 + r] = val;
    }
    __syncthreads();
    if (tid < 128) atomicAdd(&out[m0 + tid], part[0][tid] + part[1][tid]);
}

extern "C" void kernel_launch(void* const* d_in, const int* in_sizes, int n_in,
                              void* d_out, int out_size, void* d_ws, size_t ws_size,
                              hipStream_t stream) {
    const float* inputs = (const float*)d_in[0];   // [32,2048,1024]
    const float* g      = (const float*)d_in[1];   // [32,1024]
    const float* WO     = (const float*)d_in[2];   // [1024,1024]
    const float* WG     = (const float*)d_in[3];   // [1024,1024]
    const float* v      = (const float*)d_in[4];   // [1,1024]
    float* out = (float*)d_out;

    unsigned short* WOb = (unsigned short*)d_ws;                       // 2 MB bf16 WO (tiled)
    float* term2 = (float*)((char*)d_ws + (size_t)SZ * DD * 2);        // 128 KB fp32

    (void)hipMemsetAsync(d_out, 0, sizeof(float) * MM, stream);
    prep_kernel<<<1024 + 512, 256, 0, stream>>>(WO, WG, g, WOb, term2);
    fused_main<<<(MM / 128) * (SZ / 256), 256, 0, stream>>>(inputs, WOb, term2, v, out);
}

// Round 4
// 518.313 us; speedup vs baseline: 1.1094x; 1.0304x over previous
//
#include <hip/hip_runtime.h>
#include <hip/hip_bf16.h>

// Problem: B=32, S=2048, D=1024, SIZE=1024
//   term1[b,s,k] = sum_d WO[k,d]*inputs[b,s,d]   (GEMM M=65536,N=1024,K=1024)
//   term2[b,k]   = sum_d WG[k,d]*g[b,d]
//   out[b,s]     = sum_k v[k]*tanh(term1+term2)
#define BB   32
#define SS   2048
#define DD   1024
#define SZ   1024
#define MM   (BB*SS)   // 65536

typedef short bf16x8 __attribute__((ext_vector_type(8)));
typedef float f32x4  __attribute__((ext_vector_type(4)));

__device__ __forceinline__ unsigned short f2bf(float x) {
    // round-to-nearest-even fp32 -> bf16 (inputs are finite normals)
    unsigned u = __float_as_uint(x);
    u += 0x7fffu + ((u >> 16) & 1u);
    return (unsigned short)(u >> 16);
}
__device__ __forceinline__ unsigned pack2_bf16(float a, float b) {
    return (unsigned)f2bf(a) | ((unsigned)f2bf(b) << 16);
}
__device__ __forceinline__ unsigned cvtpk_bf16(float lo, float hi) {
    // v_cvt_pk_bf16_f32: dst.lo16 = bf16(lo), dst.hi16 = bf16(hi), RNE.
    // Non-volatile, no clobbers -> compiler may schedule/CSE freely.
    unsigned r;
    asm("v_cvt_pk_bf16_f32 %0, %1, %2" : "=v"(r) : "v"(lo), "v"(hi));
    return r;
}

__device__ __forceinline__ float ftanh(float x) {
    // tanh(x) = 1 - 2/(exp(2x)+1); saturates correctly for large |x|
    float e = __expf(2.0f * x);
    return 1.0f - 2.0f / (e + 1.0f);
}

// ---------------- prep ------------------------------------------------------
// WO fp32 -> bf16 in TILED layout WOb[kt=d>>5][kg=(d>>3)&3][q][d&7]
//   (main kernel's linear global_load_lds then yields conflict-free
//    [kg][n][8] LDS tiles for the B fragments)
// term2 = WG @ g[b]: one wave per 16 k's, 64-lane coalesced dot + shuffle.
__global__ void prep_kernel(const float* __restrict__ WO,
                            const float* __restrict__ WG,
                            const float* __restrict__ g,
                            unsigned short* __restrict__ WOb,
                            float* __restrict__ term2) {
    int bid = blockIdx.x, tid = threadIdx.x;
    if (bid < 1024) {
        int q = bid;            // WO row (the GEMM n index)
        int d = tid * 4;        // 4 consecutive d per thread
        float4 w = *(const float4*)(WO + (size_t)q * DD + d);
        unsigned p0 = pack2_bf16(w.x, w.y), p1 = pack2_bf16(w.z, w.w);
        int dst = ((d >> 5) * 4096 + ((d >> 3) & 3) * 1024 + q) * 8 + (d & 7);
        *(uint2*)&WOb[dst] = make_uint2(p0, p1);
    } else {
        int id    = bid - 1024;            // 0..511
        int b     = id >> 4;               // batch 0..31
        int wave  = tid >> 6, lane = tid & 63;
        int kbase = (id & 15) * 64 + wave * 16;
        const float* gr = g + (size_t)b * DD + lane * 16;
        float4 g0 = *(const float4*)(gr + 0);
        float4 g1 = *(const float4*)(gr + 4);
        float4 g2 = *(const float4*)(gr + 8);
        float4 g3 = *(const float4*)(gr + 12);
        #pragma unroll
        for (int i = 0; i < 16; i++) {
            int k = kbase + i;
            const float* wr = WG + (size_t)k * DD + lane * 16;
            float4 a0 = *(const float4*)(wr + 0);
            float4 a1 = *(const float4*)(wr + 4);
            float4 a2 = *(const float4*)(wr + 8);
            float4 a3 = *(const float4*)(wr + 12);
            float s = a0.x*g0.x + a0.y*g0.y + a0.z*g0.z + a0.w*g0.w
                    + a1.x*g1.x + a1.y*g1.y + a1.z*g1.z + a1.w*g1.w
                    + a2.x*g2.x + a2.y*g2.y + a2.z*g2.z + a2.w*g2.w
                    + a3.x*g3.x + a3.y*g3.y + a3.z*g3.z + a3.w*g3.w;
            #pragma unroll
            for (int m = 1; m < 64; m <<= 1) s += __shfl_xor(s, m);
            if (lane == 0) term2[b * SZ + k] = s;
        }
    }
}

// ---------------- main: fused GEMM + tanh + v-reduction ---------------------
// block tile 128(M) x 256(N), BK=32; 4 waves, each 64x128 (4x8 of 16x16x32).
// Depth-2 pipeline: B triple-buffered (DMA issued 2 iters ahead of use),
// A reg-prefetched 1 iter ahead, cvt via v_cvt_pk_bf16_f32 (1 inst/pair
// instead of ~10 -- round-2 profile showed conversion VALU > MFMA cycles).
// Iteration order (sched_barrier-pinned):
//   STAGE_B(t+2)                 -- DMA issue, lands ~1.3 iters later
//   COMPUTE(t)                   -- inputs settled at previous barrier
//   WRITE_A(t+1)                 -- implicit vmcnt retires B(t+1),A(t+1);
//                                   both have had a full iteration of cover
//   LOAD_A(t+2)                  -- reg prefetch reusing areg
//   vmcnt(8) [no-op fence] ; lgkmcnt(0) ; s_barrier
// Steady state: 8 vmem ops (B(t+2)x4 + A(t+2)x4) stay in flight across the
// barrier -- never drained (T4). LDS layouts [kg][row][8]: each 16-lane
// ds_read_b128 group reads 256 contiguous bytes -> conflict-free.
__global__ __launch_bounds__(256, 2) void fused_main(
    const float* __restrict__ Ain,            // [MM, DD] fp32
    const unsigned short* __restrict__ WOb,   // tiled bf16 (see prep)
    const float* __restrict__ term2,          // [BB, SZ] fp32
    const float* __restrict__ v,              // [SZ] fp32
    float* __restrict__ out) {                // [MM] fp32 (pre-zeroed)
    __shared__ unsigned short Abuf[2][4096];  // [buf][kg 0..3][row 0..127][8]
    __shared__ unsigned short Bbuf[3][8192];  // [buf][kg 0..3][n 0..255][8]
    __shared__ float part[2][128];

    const int tid  = threadIdx.x;
    const int wave = tid >> 6;
    const int lane = tid & 63;
    const int wm  = wave & 1, wn = wave >> 1;
    const int l15 = lane & 15;
    const int k8  = lane >> 4;                // k-group 0..3 (8 bf16 each)

    // XCD-aware bijective swizzle (2048 % 8 == 0): each XCD owns contiguous
    // logical blocks -> the 4 n-tiles of an m-tile share A via that XCD's L2.
    const int bid     = blockIdx.x;
    const int logical = (bid & 7) * 256 + (bid >> 3);
    const int ntile = logical & 3;
    const int mtile = logical >> 2;
    const int m0 = mtile * 128;
    const int n0 = ntile * 256;
    const int bidx = m0 >> 11;                // batch index (128 | 2048)

    f32x4 acc[4][8];
    #pragma unroll
    for (int i = 0; i < 4; i++)
        #pragma unroll
        for (int j = 0; j < 8; j++) acc[i][j] = (f32x4){0.f, 0.f, 0.f, 0.f};

    float4 areg[4];

    // --- staging helpers ---
    auto LOAD_A = [&](int k0) {               // fp32 tile -> regs (4x dwordx4)
        #pragma unroll
        for (int r = 0; r < 4; r++) {
            int row = r * 32 + (tid >> 3);
            areg[r] = *(const float4*)(Ain + (size_t)(m0 + row) * DD + k0 + (tid & 7) * 4);
        }
    };
    auto WRITE_A = [&](int buf) {             // regs -> bf16 LDS [kg][row][8]
        const int q = tid & 7, kg = q >> 1, half = q & 1;
        #pragma unroll
        for (int r = 0; r < 4; r++) {
            int row = r * 32 + (tid >> 3);
            unsigned p0 = cvtpk_bf16(areg[r].x, areg[r].y);
            unsigned p1 = cvtpk_bf16(areg[r].z, areg[r].w);
            *(uint2*)&Abuf[buf][(kg * 128 + row) * 8 + half * 4] = make_uint2(p0, p1);
        }
    };
    auto STAGE_B = [&](int buf, int kt) {     // tiled bf16 -> LDS via DMA
        #pragma unroll
        for (int r = 0; r < 4; r++) {         // round r fills kg=r, n=tid
            const unsigned short* src = WOb + ((size_t)(kt * 4 + r) * 1024 + n0 + tid) * 8;
            __builtin_amdgcn_global_load_lds(
                (const __attribute__((address_space(1))) void*)src,
                (__attribute__((address_space(3))) void*)(&Bbuf[buf][(r * 256 + tid) * 8]),
                16, 0, 0);
        }
    };
    auto COMPUTE = [&](int abuf, int bbuf) {
        bf16x8 afr[4], bfr[8];
        const int aoff = (k8 * 128 + wm * 64 + l15) * 8;
        const int boff = (k8 * 256 + wn * 128 + l15) * 8;
        #pragma unroll
        for (int mi = 0; mi < 4; mi++)
            afr[mi] = *(const bf16x8*)&Abuf[abuf][aoff + mi * 128];
        #pragma unroll
        for (int ni = 0; ni < 8; ni++)
            bfr[ni] = *(const bf16x8*)&Bbuf[bbuf][boff + ni * 128];
        __builtin_amdgcn_s_setprio(1);
        #pragma unroll
        for (int ni = 0; ni < 8; ni++)
            #pragma unroll
            for (int mi = 0; mi < 4; mi++)
                acc[mi][ni] = __builtin_amdgcn_mfma_f32_16x16x32_bf16(
                    afr[mi], bfr[ni], acc[mi][ni], 0, 0, 0);
        __builtin_amdgcn_s_setprio(0);
    };

    // --- prologue: Abuf0=A(0), Bbuf0=B(0); in flight: B(1)->Bbuf1, A(1)->areg
    LOAD_A(0);                                 // issue A(0)
    __builtin_amdgcn_sched_barrier(0);
    STAGE_B(0, 0);                             // issue B(0)
    __builtin_amdgcn_sched_barrier(0);
    WRITE_A(0);                                // implicit wait on A(0)
    __builtin_amdgcn_sched_barrier(0);
    STAGE_B(1, 1);                             // issue B(1)  (order: B before A)
    __builtin_amdgcn_sched_barrier(0);
    LOAD_A(32);                                // issue A(1)
    __builtin_amdgcn_sched_barrier(0);
    asm volatile("s_waitcnt vmcnt(8)" ::: "memory");   // B(0) landed
    asm volatile("s_waitcnt lgkmcnt(0)" ::: "memory"); // A(0) ds_writes done
    __builtin_amdgcn_sched_barrier(0);
    __builtin_amdgcn_s_barrier();

    // --- main loop ---
    int bc = 0;                                // Bbuf index holding B(t)
    for (int t = 0; t < 31; ++t) {
        const int ab = t & 1;
        const int bs = (bc + 2 >= 3) ? bc - 1 : bc + 2;   // (bc+2)%3
        const int tn = (t + 2 <= 31) ? t + 2 : 31;        // clamped prefetch idx
        STAGE_B(bs, tn);                       // B(t+2) issue (buffer free since
        __builtin_amdgcn_sched_barrier(0);     //  its readers passed t-1 barrier)
        COMPUTE(ab, bc);                       // inputs settled at prev barrier
        __builtin_amdgcn_sched_barrier(0);
        WRITE_A(ab ^ 1);                       // A(t+1): implicit counted wait
        __builtin_amdgcn_sched_barrier(0);
        LOAD_A(tn << 5);                       // A(t+2) issue
        __builtin_amdgcn_sched_barrier(0);
        asm volatile("s_waitcnt vmcnt(8)" ::: "memory");   // fence (steady: no-op)
        asm volatile("s_waitcnt lgkmcnt(0)" ::: "memory"); // A writes visible
        __builtin_amdgcn_sched_barrier(0);
        __builtin_amdgcn_s_barrier();
        bc = (bc + 1 >= 3) ? 0 : bc + 1;
    }
    COMPUTE(1, bc);                            // t=31: Abuf1, Bbuf[31%3=1]

    // --- epilogue: tanh(term1+term2)*v, reduce over this block's 256 cols ---
    float rsum[4][4];
    #pragma unroll
    for (int mi = 0; mi < 4; mi++)
        #pragma unroll
        for (int r = 0; r < 4; r++) rsum[mi][r] = 0.f;

    #pragma unroll
    for (int ni = 0; ni < 8; ni++) {
        int gn = n0 + wn * 128 + ni * 16 + l15;   // C/D: col = lane&15
        float t2 = term2[bidx * SZ + gn];
        float vv = v[gn];
        #pragma unroll
        for (int mi = 0; mi < 4; mi++)
            #pragma unroll
            for (int r = 0; r < 4; r++)
                rsum[mi][r] += ftanh(acc[mi][ni][r] + t2) * vv;
    }
    // reduce across the 16 col-lanes (butterfly within 16-lane groups)
    #pragma unroll
    for (int mi = 0; mi < 4; mi++)
        #pragma unroll
        for (int r = 0; r < 4; r++) {
            float s = rsum[mi][r];
            s += __shfl_xor(s, 1, 16);
            s += __shfl_xor(s, 2, 16);
            s += __shfl_xor(s, 4, 16);
            s += __shfl_xor(s, 8, 16);
            rsum[mi][r] = s;
        }
    // lane l15 == mi*4+r publishes row (wm*64 + mi*16 + k8*4 + r)
    float val = 0.f;
    #pragma unroll
    for (int mi = 0; mi < 4; mi++)
        #pragma unroll
        for (int r = 0; r < 4; r++)
            if (l15 == mi * 4 + r) val = rsum[mi][r];
    {
        int mi = l15 >> 2, r = l15 & 3;
        part[wn][wm * 64 + mi * 16 + k8 * 4 + r] = val;
    }
    __syncthreads();
    if (tid < 128) atomicAdd(&out[m0 + tid], part[0][tid] + part[1][tid]);
}

extern "C" void kernel_launch(void* const* d_in, const int* in_sizes, int n_in,
                              void* d_out, int out_size, void* d_ws, size_t ws_size,
                              hipStream_t stream) {
    const float* inputs = (const float*)d_in[0];   // [32,2048,1024]
    const float* g      = (const float*)d_in[1];   // [32,1024]
    const float* WO     = (const float*)d_in[2];   // [1024,1024]
    const float* WG     = (const float*)d_in[3];   // [1024,1024]
    const float* v      = (const float*)d_in[4];   // [1,1024]
    float* out = (float*)d_out;

    unsigned short* WOb = (unsigned short*)d_ws;                       // 2 MB bf16 WO (tiled)
    float* term2 = (float*)((char*)d_ws + (size_t)SZ * DD * 2);        // 128 KB fp32

    (void)hipMemsetAsync(d_out, 0, sizeof(float) * MM, stream);
    prep_kernel<<<1024 + 512, 256, 0, stream>>>(WO, WG, g, WOb, term2);
    fused_main<<<(MM / 128) * (SZ / 256), 256, 0, stream>>>(inputs, WOb, term2, v, out);
}